// Round 3
// baseline (208.613 us; speedup 1.0000x reference)
//
#include <hip/hip_runtime.h>
#include <stdint.h>

typedef __bf16 v8bf __attribute__((ext_vector_type(8)));
typedef float  v4f  __attribute__((ext_vector_type(4)));

__device__ __forceinline__ uint16_t f2bf(float f){
  union { float f; uint32_t u; } v; v.f = f;
  uint32_t r = v.u + 0x7FFFu + ((v.u >> 16) & 1u);
  return (uint16_t)(r >> 16);
}
__device__ __forceinline__ float bf2f(uint16_t u){
  union { uint32_t u; float f; } v; v.u = ((uint32_t)u) << 16; return v.f;
}
__device__ __forceinline__ v4f vzero(){ v4f z = {0.f,0.f,0.f,0.f}; return z; }

// ---- 64x64 bf16 tile staging (LDS row stride 72) ----
__device__ __forceinline__ void ld64(uint4 r[2], const uint16_t* __restrict__ g, int ldg, int tid){
  int row = tid >> 2, c = (tid & 3) * 16;
  r[0] = *(const uint4*)(g + (size_t)row * ldg + c);
  r[1] = *(const uint4*)(g + (size_t)row * ldg + c + 8);
}
__device__ __forceinline__ void st64(uint16_t* __restrict__ s, const uint4 r[2], int tid){
  int row = tid >> 2, c = (tid & 3) * 16;
  *(uint4*)(s + row * 72 + c) = r[0];
  *(uint4*)(s + row * 72 + c + 8) = r[1];
}
__device__ __forceinline__ void stage64(uint16_t* s, const uint16_t* g, int ldg, int tid){
  uint4 r[2]; ld64(r, g, ldg, tid); st64(s, r, tid);
}

// ---------------- prep ----------------
__global__ void k_xcast(const float* __restrict__ X, uint16_t* __restrict__ Xb){
  int i = (blockIdx.x * 256 + threadIdx.x) * 8;
  float4 a = *(const float4*)(X + i);
  float4 b = *(const float4*)(X + i + 4);
  union { uint16_t h[8]; uint4 v; } o;
  o.h[0]=f2bf(a.x); o.h[1]=f2bf(a.y); o.h[2]=f2bf(a.z); o.h[3]=f2bf(a.w);
  o.h[4]=f2bf(b.x); o.h[5]=f2bf(b.y); o.h[6]=f2bf(b.z); o.h[7]=f2bf(b.w);
  *(uint4*)(Xb + i) = o.v;
}

__global__ void k_weff(const float* __restrict__ Wq, const float* __restrict__ Aq, const float* __restrict__ Bq,
                       const float* __restrict__ Wk, const float* __restrict__ Ak, const float* __restrict__ Bk,
                       const float* __restrict__ Wv, const float* __restrict__ Av, const float* __restrict__ Bv,
                       uint16_t* __restrict__ Wo){
  int y = blockIdx.y;
  const float* W  = (y == 0) ? Wq : (y == 1) ? Wk : Wv;
  const float* A  = (y == 0) ? Aq : (y == 1) ? Ak : Av;
  const float* Bm = (y == 0) ? Bq : (y == 1) ? Bk : Bv;
  int idx = blockIdx.x * 256 + threadIdx.x;
  int f = idx >> 10, k = idx & 1023;
  float acc = W[idx];
  #pragma unroll
  for (int r = 0; r < 16; ++r) acc += Bm[f * 16 + r] * A[r * 1024 + k];
  Wo[(size_t)y * 1048576 + idx] = f2bf(acc);
}

// ---------------- fused QKV projection GEMM ----------------
// C[4096,3072] = Xb[4096,1024] @ Weff[3072,1024]^T + bias
__global__ __launch_bounds__(256, 2)
void k_gemm(const uint16_t* __restrict__ Ag, const uint16_t* __restrict__ Bg,
            const float* __restrict__ qb, const float* __restrict__ kb,
            const float* __restrict__ vb, uint16_t* __restrict__ Cg){
  __shared__ __align__(16) uint16_t smem[2 * 128 * 72];   // As/Bs, reused as Ct
  uint16_t* As = smem;
  uint16_t* Bs = smem + 128 * 72;
  int tid = threadIdx.x, lane = tid & 63, wid = tid >> 6;
  int l15 = lane & 15, lg = lane >> 4;
  int wr = wid >> 1, wc = wid & 1;
  int bid = blockIdx.x, xcd = bid & 7, idx = bid >> 3;
  int nb = xcd * 96 + idx;                 // 768 blocks, 96/XCD chunk
  int mt = nb / 24, nt = nb - mt * 24;
  int m0 = mt * 128, n0 = nt * 128;
  int r0 = tid >> 3, c8 = (tid & 7) * 8;
  const uint16_t* Ap = Ag + (size_t)(m0 + r0) * 1024 + c8;
  const uint16_t* Bp = Bg + (size_t)(n0 + r0) * 1024 + c8;
  uint4 ra[4], rb[4];
  #pragma unroll
  for (int c = 0; c < 4; ++c){
    ra[c] = *(const uint4*)(Ap + (size_t)c * 32 * 1024);
    rb[c] = *(const uint4*)(Bp + (size_t)c * 32 * 1024);
  }
  v4f acc[4][4];
  #pragma unroll
  for (int a = 0; a < 4; ++a)
    #pragma unroll
    for (int c = 0; c < 4; ++c) acc[a][c] = vzero();

  for (int kk = 0; kk < 16; ++kk){
    __syncthreads();
    #pragma unroll
    for (int c = 0; c < 4; ++c){
      *(uint4*)(As + (r0 + c * 32) * 72 + c8) = ra[c];
      *(uint4*)(Bs + (r0 + c * 32) * 72 + c8) = rb[c];
    }
    __syncthreads();
    if (kk < 15){
      #pragma unroll
      for (int c = 0; c < 4; ++c){
        ra[c] = *(const uint4*)(Ap + (size_t)c * 32 * 1024 + (kk + 1) * 64);
        rb[c] = *(const uint4*)(Bp + (size_t)c * 32 * 1024 + (kk + 1) * 64);
      }
    }
    #pragma unroll
    for (int kc = 0; kc < 2; ++kc){
      v8bf af[4], bfr[4];
      #pragma unroll
      for (int mi = 0; mi < 4; ++mi)
        af[mi] = *(const v8bf*)(As + (wr * 64 + mi * 16 + l15) * 72 + kc * 32 + lg * 8);
      #pragma unroll
      for (int nj = 0; nj < 4; ++nj)
        bfr[nj] = *(const v8bf*)(Bs + (wc * 64 + nj * 16 + l15) * 72 + kc * 32 + lg * 8);
      #pragma unroll
      for (int mi = 0; mi < 4; ++mi)
        #pragma unroll
        for (int nj = 0; nj < 4; ++nj)
          acc[mi][nj] = __builtin_amdgcn_mfma_f32_16x16x32_bf16(af[mi], bfr[nj], acc[mi][nj], 0, 0, 0);
    }
  }
  // ---- epilogue: stage C tile in LDS (stride 132), store vectorized ----
  __syncthreads();                      // done with As/Bs
  uint16_t* Ct = smem;                  // 128*132 = 16896 elems (33792 B)
  #pragma unroll
  for (int nj = 0; nj < 4; ++nj){
    int n = n0 + wc * 64 + nj * 16 + l15;
    float bv_ = (n < 1024) ? qb[n] : (n < 2048) ? kb[n - 1024] : vb[n - 2048];
    #pragma unroll
    for (int mi = 0; mi < 4; ++mi)
      #pragma unroll
      for (int r = 0; r < 4; ++r){
        int ml = wr * 64 + mi * 16 + lg * 4 + r;
        Ct[ml * 132 + wc * 64 + nj * 16 + l15] = f2bf(acc[mi][nj][r] + bv_);
      }
  }
  __syncthreads();
  {
    int row = tid >> 1;                 // 0..127
    int c0  = (tid & 1) * 64;           // 0 or 64
    uint16_t* gp = Cg + (size_t)(m0 + row) * 3072 + n0 + c0;
    const uint16_t* sp = Ct + row * 132 + c0;
    #pragma unroll
    for (int c = 0; c < 8; ++c)
      *(uint4*)(gp + c * 8) = *(const uint4*)(sp + c * 8);
  }
}

// ---------------- pass 1: column sums (balanced pair of j-tiles) ----------------
__global__ __launch_bounds__(256, 2)
void k_colsum(const uint16_t* __restrict__ QKVg, float* __restrict__ csum){
  __shared__ __align__(16) uint16_t Ka[64 * 72], KbS[64 * 72], Qs[64 * 72];
  __shared__ float colacc[128];
  int tid = threadIdx.x, lane = tid & 63, l15 = lane & 15, lg = lane >> 4, wid = tid >> 6;
  int wr = wid >> 1, wc = wid & 1;
  int bid = blockIdx.x, xcd = bid & 7, idx = bid >> 3;
  int bh = xcd * 8 + (idx & 7);
  int p4 = idx >> 3; int pr = (p4 < 4) ? p4 : 11 - p4;
  int b = bh >> 4, h = bh & 15;
  int jtA = pr, jtB = 15 - pr;
  const uint16_t* Qb = QKVg + (size_t)b * 1024 * 3072 + h * 64;
  const uint16_t* Kb = QKVg + (size_t)b * 1024 * 3072 + 1024 + h * 64;
  stage64(Ka,  Kb + (size_t)jtA * 64 * 3072, 3072, tid);
  stage64(KbS, Kb + (size_t)jtB * 64 * 3072, 3072, tid);
  if (tid < 128) colacc[tid] = 0.f;
  uint4 rq[2]; ld64(rq, Qb + (size_t)jtA * 64 * 3072, 3072, tid);
  float cpA[2] = {0.f, 0.f}, cpB[2] = {0.f, 0.f};
  for (int it = jtA; it < 16; ++it){
    __syncthreads();
    st64(Qs, rq, tid);
    __syncthreads();
    if (it < 15) ld64(rq, Qb + (size_t)(it + 1) * 64 * 3072, 3072, tid);
    bool doB = (it >= jtB);
    v4f sa[2][2], sb[2][2];
    #pragma unroll
    for (int a = 0; a < 2; ++a)
      #pragma unroll
      for (int c = 0; c < 2; ++c){ sa[a][c] = vzero(); sb[a][c] = vzero(); }
    #pragma unroll
    for (int kc = 0; kc < 2; ++kc){
      v8bf aq[2], k1[2], k2[2];
      #pragma unroll
      for (int mi = 0; mi < 2; ++mi)
        aq[mi] = *(const v8bf*)(Qs + (wr * 32 + mi * 16 + l15) * 72 + kc * 32 + lg * 8);
      #pragma unroll
      for (int nj = 0; nj < 2; ++nj)
        k1[nj] = *(const v8bf*)(Ka + (wc * 32 + nj * 16 + l15) * 72 + kc * 32 + lg * 8);
      #pragma unroll
      for (int mi = 0; mi < 2; ++mi)
        #pragma unroll
        for (int nj = 0; nj < 2; ++nj)
          sa[mi][nj] = __builtin_amdgcn_mfma_f32_16x16x32_bf16(aq[mi], k1[nj], sa[mi][nj], 0, 0, 0);
      if (doB){
        #pragma unroll
        for (int nj = 0; nj < 2; ++nj)
          k2[nj] = *(const v8bf*)(KbS + (wc * 32 + nj * 16 + l15) * 72 + kc * 32 + lg * 8);
        #pragma unroll
        for (int mi = 0; mi < 2; ++mi)
          #pragma unroll
          for (int nj = 0; nj < 2; ++nj)
            sb[mi][nj] = __builtin_amdgcn_mfma_f32_16x16x32_bf16(aq[mi], k2[nj], sb[mi][nj], 0, 0, 0);
      }
    }
    #pragma unroll
    for (int mi = 0; mi < 2; ++mi)
      #pragma unroll
      for (int nj = 0; nj < 2; ++nj)
        #pragma unroll
        for (int r = 0; r < 4; ++r){
          int il = wr * 32 + mi * 16 + lg * 4 + r;
          int jl = wc * 32 + nj * 16 + l15;
          if (it > jtA || il >= jl) cpA[nj] += __expf(sa[mi][nj][r] * 0.03125f);
          if (doB && (it > jtB || il >= jl)) cpB[nj] += __expf(sb[mi][nj][r] * 0.03125f);
        }
  }
  #pragma unroll
  for (int nj = 0; nj < 2; ++nj){
    float v = cpA[nj];
    v += __shfl_xor(v, 16, 64); v += __shfl_xor(v, 32, 64);
    if (lane < 16) atomicAdd(&colacc[wc * 32 + nj * 16 + l15], v);
    float w = cpB[nj];
    w += __shfl_xor(w, 16, 64); w += __shfl_xor(w, 32, 64);
    if (lane < 16) atomicAdd(&colacc[64 + wc * 32 + nj * 16 + l15], w);
  }
  __syncthreads();
  if (tid < 64)       csum[(size_t)bh * 1024 + jtA * 64 + tid] = colacc[tid];
  else if (tid < 128) csum[(size_t)bh * 1024 + jtB * 64 + (tid - 64)] = colacc[tid];
}

// ---------------- V' = V * mask/colsum, transposed to [bh][64 d][1024 j] ----------------
__global__ __launch_bounds__(256)
void k_vprep(const uint16_t* __restrict__ QKVg, const float* __restrict__ csum,
             const float* __restrict__ mask, uint16_t* __restrict__ Vp){
  __shared__ __align__(16) uint16_t Vs[128 * 72];
  __shared__ float scb[128];
  int tid = threadIdx.x;
  int bid = blockIdx.x, xcd = bid & 7, idx = bid >> 3;
  int bh = xcd * 8 + (idx & 7);
  int jt = idx >> 3;
  int b = bh >> 4, h = bh & 15;
  int j0 = jt * 128;
  stage64(Vs,           QKVg + ((size_t)(b * 1024 + j0)) * 3072 + 2048 + h * 64, 3072, tid);
  stage64(Vs + 64 * 72, QKVg + ((size_t)(b * 1024 + j0 + 64)) * 3072 + 2048 + h * 64, 3072, tid);
  if (tid < 128) scb[tid] = mask[b * 1024 + j0 + tid] / csum[(size_t)bh * 1024 + j0 + tid];
  __syncthreads();
  int d = tid >> 2, jc = (tid & 3) * 32;
  #pragma unroll
  for (int g8 = 0; g8 < 4; ++g8){
    union { uint16_t h[8]; uint4 v; } o;
    #pragma unroll
    for (int e = 0; e < 8; ++e){
      int j = jc + g8 * 8 + e;
      o.h[e] = f2bf(bf2f(Vs[j * 72 + d]) * scb[j]);
    }
    *(uint4*)(Vp + (size_t)bh * 65536 + (size_t)d * 1024 + j0 + jc + g8 * 8) = o.v;
  }
}

// ---------------- pass 2: O = exp(S) @ V' (balanced pair of i-tiles) ----------------
__global__ __launch_bounds__(256, 2)
void k_attnout(const uint16_t* __restrict__ QKVg, const uint16_t* __restrict__ Vp,
               float* __restrict__ out){
  __shared__ __align__(16) uint16_t Qs[128 * 72], Ks[64 * 72], Vt[64 * 72], Ps[128 * 72];
  int tid = threadIdx.x, lane = tid & 63, l15 = lane & 15, lg = lane >> 4, wid = tid >> 6;
  int wr = wid >> 1, wc = wid & 1;
  int bid = blockIdx.x, xcd = bid & 7, idx = bid >> 3;
  int bh = xcd * 8 + (idx & 7);
  int p4 = idx >> 3; int pr = (p4 < 4) ? p4 : 11 - p4;
  int b = bh >> 4, h = bh & 15;
  int itA = pr, itB = 15 - pr;
  const uint16_t* Qb = QKVg + (size_t)b * 1024 * 3072 + h * 64;
  const uint16_t* Kb = QKVg + (size_t)b * 1024 * 3072 + 1024 + h * 64;
  const uint16_t* Vb = Vp + (size_t)bh * 65536;
  stage64(Qs,           Qb + (size_t)itA * 64 * 3072, 3072, tid);
  stage64(Qs + 64 * 72, Qb + (size_t)itB * 64 * 3072, 3072, tid);
  uint4 rk[2], rv[2];
  ld64(rk, Kb, 3072, tid);
  ld64(rv, Vb, 1024, tid);
  v4f oacc[2][2][2];
  #pragma unroll
  for (int a = 0; a < 2; ++a)
    #pragma unroll
    for (int c = 0; c < 2; ++c)
      #pragma unroll
      for (int d = 0; d < 2; ++d) oacc[a][c][d] = vzero();

  for (int jt = 0; jt <= itB; ++jt){
    __syncthreads();
    st64(Ks, rk, tid);
    st64(Vt, rv, tid);
    __syncthreads();
    if (jt < itB){
      ld64(rk, Kb + (size_t)(jt + 1) * 64 * 3072, 3072, tid);
      ld64(rv, Vb + (jt + 1) * 64, 1024, tid);
    }
    #pragma unroll
    for (int half = 0; half < 2; ++half){
      int ith = half ? itB : itA;
      if (jt <= ith){
        v4f sacc[2][2];
        #pragma unroll
        for (int a = 0; a < 2; ++a)
          #pragma unroll
          for (int c = 0; c < 2; ++c) sacc[a][c] = vzero();
        #pragma unroll
        for (int kc = 0; kc < 2; ++kc){
          v8bf ak[2], aq[2];
          #pragma unroll
          for (int mj = 0; mj < 2; ++mj)
            ak[mj] = *(const v8bf*)(Ks + (wr * 32 + mj * 16 + l15) * 72 + kc * 32 + lg * 8);
          #pragma unroll
          for (int ni = 0; ni < 2; ++ni)
            aq[ni] = *(const v8bf*)(Qs + (half * 64 + wc * 32 + ni * 16 + l15) * 72 + kc * 32 + lg * 8);
          #pragma unroll
          for (int mj = 0; mj < 2; ++mj)
            #pragma unroll
            for (int ni = 0; ni < 2; ++ni)
              sacc[mj][ni] = __builtin_amdgcn_mfma_f32_16x16x32_bf16(ak[mj], aq[ni], sacc[mj][ni], 0, 0, 0);
        }
        bool diag = (jt == ith);
        #pragma unroll
        for (int mj = 0; mj < 2; ++mj)
          #pragma unroll
          for (int ni = 0; ni < 2; ++ni){
            int iL = wc * 32 + ni * 16 + l15;
            int jb = wr * 32 + mj * 16 + lg * 4;
            float e0 = (!diag || jb + 0 <= iL) ? __expf(sacc[mj][ni][0] * 0.03125f) : 0.f;
            float e1 = (!diag || jb + 1 <= iL) ? __expf(sacc[mj][ni][1] * 0.03125f) : 0.f;
            float e2 = (!diag || jb + 2 <= iL) ? __expf(sacc[mj][ni][2] * 0.03125f) : 0.f;
            float e3 = (!diag || jb + 3 <= iL) ? __expf(sacc[mj][ni][3] * 0.03125f) : 0.f;
            uint2 pk;
            pk.x = (uint32_t)f2bf(e0) | ((uint32_t)f2bf(e1) << 16);
            pk.y = (uint32_t)f2bf(e2) | ((uint32_t)f2bf(e3) << 16);
            *(uint2*)(Ps + (half * 64 + iL) * 72 + jb) = pk;
          }
      }
    }
    __syncthreads();
    #pragma unroll
    for (int half = 0; half < 2; ++half){
      int ith = half ? itB : itA;
      if (jt <= ith){
        #pragma unroll
        for (int kc = 0; kc < 2; ++kc){
          v8bf pa[2], vb_[2];
          #pragma unroll
          for (int mi = 0; mi < 2; ++mi)
            pa[mi] = *(const v8bf*)(Ps + (half * 64 + wr * 32 + mi * 16 + l15) * 72 + kc * 32 + lg * 8);
          #pragma unroll
          for (int nj = 0; nj < 2; ++nj)
            vb_[nj] = *(const v8bf*)(Vt + (wc * 32 + nj * 16 + l15) * 72 + kc * 32 + lg * 8);
          #pragma unroll
          for (int mi = 0; mi < 2; ++mi)
            #pragma unroll
            for (int nj = 0; nj < 2; ++nj)
              oacc[half][mi][nj] = __builtin_amdgcn_mfma_f32_16x16x32_bf16(pa[mi], vb_[nj], oacc[half][mi][nj], 0, 0, 0);
        }
      }
    }
  }
  #pragma unroll
  for (int half = 0; half < 2; ++half){
    int ith = half ? itB : itA;
    #pragma unroll
    for (int mi = 0; mi < 2; ++mi)
      #pragma unroll
      for (int nj = 0; nj < 2; ++nj)
        #pragma unroll
        for (int r = 0; r < 4; ++r){
          int ig = ith * 64 + wr * 32 + mi * 16 + lg * 4 + r;
          int d  = wc * 32 + nj * 16 + l15;
          out[((size_t)(b * 1024) + ig) * 1024 + h * 64 + d] = oacc[half][mi][nj][r];
        }
  }
}

extern "C" void kernel_launch(void* const* d_in, const int* in_sizes, int n_in,
                              void* d_out, int out_size, void* d_ws, size_t ws_size,
                              hipStream_t stream) {
  (void)in_sizes; (void)n_in; (void)out_size; (void)ws_size;
  const float* X    = (const float*)d_in[0];
  const float* mask = (const float*)d_in[1];
  const float* Wq   = (const float*)d_in[2];
  const float* bq   = (const float*)d_in[3];
  const float* Wk   = (const float*)d_in[4];
  const float* bk   = (const float*)d_in[5];
  const float* Wv   = (const float*)d_in[6];
  const float* bv   = (const float*)d_in[7];
  const float* Aq   = (const float*)d_in[8];
  const float* Bq   = (const float*)d_in[9];
  const float* Ak   = (const float*)d_in[10];
  const float* Bk   = (const float*)d_in[11];
  const float* Av   = (const float*)d_in[12];
  const float* Bv   = (const float*)d_in[13];
  float* out = (float*)d_out;

  uint16_t* Xb   = (uint16_t*)d_ws;                        // 8 MB
  uint16_t* Weff = Xb + (size_t)4096 * 1024;               // 6 MB  [3072][1024]
  uint16_t* QKV  = Weff + (size_t)3 * 1024 * 1024;         // 24 MB [4096][3072]
  uint16_t* Vp   = QKV + (size_t)4096 * 3072;              // 8 MB  [64][64][1024]
  float*    csum = (float*)(Vp + (size_t)64 * 64 * 1024);  // 256 KB

  k_xcast<<<2048, 256, 0, stream>>>(X, Xb);
  k_weff<<<dim3(4096, 3), 256, 0, stream>>>(Wq, Aq, Bq, Wk, Ak, Bk, Wv, Av, Bv, Weff);
  k_gemm<<<768, 256, 0, stream>>>(Xb, Weff, bq, bk, bv, QKV);
  k_colsum<<<512, 256, 0, stream>>>(QKV, csum);
  k_vprep<<<512, 256, 0, stream>>>(QKV, csum, mask, Vp);
  k_attnout<<<512, 256, 0, stream>>>(QKV, Vp, out);
}

// Round 4
// 130.495 us; speedup vs baseline: 1.5986x; 1.5986x over previous
//
#include <hip/hip_runtime.h>
#include <stdint.h>

typedef __bf16 v8bf __attribute__((ext_vector_type(8)));
typedef float  v4f  __attribute__((ext_vector_type(4)));

__device__ __forceinline__ uint16_t f2bf(float f){
  union { float f; uint32_t u; } v; v.f = f;
  uint32_t r = v.u + 0x7FFFu + ((v.u >> 16) & 1u);
  return (uint16_t)(r >> 16);
}
__device__ __forceinline__ float bf2f(uint16_t u){
  union { uint32_t u; float f; } v; v.u = ((uint32_t)u) << 16; return v.f;
}
__device__ __forceinline__ v4f vzero(){ v4f z = {0.f,0.f,0.f,0.f}; return z; }

// async global->LDS, 16B per lane; LDS dest is wave-uniform base + lane*16
__device__ __forceinline__ void gld16(const uint16_t* __restrict__ g, uint16_t* l){
  __builtin_amdgcn_global_load_lds((const __attribute__((address_space(1))) void*)g,
                                   (__attribute__((address_space(3))) void*)l, 16, 0, 0);
}

// ---- 64x64 bf16 tile staging (LDS row stride 72) ---- (attn kernels)
__device__ __forceinline__ void ld64(uint4 r[2], const uint16_t* __restrict__ g, int ldg, int tid){
  int row = tid >> 2, c = (tid & 3) * 16;
  r[0] = *(const uint4*)(g + (size_t)row * ldg + c);
  r[1] = *(const uint4*)(g + (size_t)row * ldg + c + 8);
}
__device__ __forceinline__ void st64(uint16_t* __restrict__ s, const uint4 r[2], int tid){
  int row = tid >> 2, c = (tid & 3) * 16;
  *(uint4*)(s + row * 72 + c) = r[0];
  *(uint4*)(s + row * 72 + c + 8) = r[1];
}
__device__ __forceinline__ void stage64(uint16_t* s, const uint16_t* g, int ldg, int tid){
  uint4 r[2]; ld64(r, g, ldg, tid); st64(s, r, tid);
}

// ---------------- prep ----------------
__global__ void k_xcast(const float* __restrict__ X, uint16_t* __restrict__ Xb){
  int i = (blockIdx.x * 256 + threadIdx.x) * 8;
  float4 a = *(const float4*)(X + i);
  float4 b = *(const float4*)(X + i + 4);
  union { uint16_t h[8]; uint4 v; } o;
  o.h[0]=f2bf(a.x); o.h[1]=f2bf(a.y); o.h[2]=f2bf(a.z); o.h[3]=f2bf(a.w);
  o.h[4]=f2bf(b.x); o.h[5]=f2bf(b.y); o.h[6]=f2bf(b.z); o.h[7]=f2bf(b.w);
  *(uint4*)(Xb + i) = o.v;
}

__global__ void k_weff(const float* __restrict__ Wq, const float* __restrict__ Aq, const float* __restrict__ Bq,
                       const float* __restrict__ Wk, const float* __restrict__ Ak, const float* __restrict__ Bk,
                       const float* __restrict__ Wv, const float* __restrict__ Av, const float* __restrict__ Bv,
                       uint16_t* __restrict__ Wo){
  int y = blockIdx.y;
  const float* W  = (y == 0) ? Wq : (y == 1) ? Wk : Wv;
  const float* A  = (y == 0) ? Aq : (y == 1) ? Ak : Av;
  const float* Bm = (y == 0) ? Bq : (y == 1) ? Bk : Bv;
  int idx = blockIdx.x * 256 + threadIdx.x;
  int f = idx >> 10, k = idx & 1023;
  float acc = W[idx];
  #pragma unroll
  for (int r = 0; r < 16; ++r) acc += Bm[f * 16 + r] * A[r * 1024 + k];
  Wo[(size_t)y * 1048576 + idx] = f2bf(acc);
}

// ---------------- fused QKV projection GEMM (m97 structure) ----------------
// C[4096,3072] = Xb[4096,1024] @ Weff[3072,1024]^T + bias
__global__ __launch_bounds__(256, 2)
void k_gemm(const uint16_t* __restrict__ Ag, const uint16_t* __restrict__ Bg,
            const float* __restrict__ qb, const float* __restrict__ kb,
            const float* __restrict__ vb, uint16_t* __restrict__ Cg){
  __shared__ __align__(16) uint16_t smem[16896];   // As[8192] Bs[8192]; reused as Ct[128*132]
  uint16_t* As = smem;
  uint16_t* Bs = smem + 8192;
  int tid = threadIdx.x, lane = tid & 63, wid = tid >> 6;
  int l15 = lane & 15, lg = lane >> 4;
  int wr = wid >> 1, wc = wid & 1;
  int bid = blockIdx.x, xcd = bid & 7, idx = bid >> 3;
  int nb = xcd * 96 + idx;                 // 768 blocks, 96/XCD chunk
  int mt = nb / 24, nt = nb - mt * 24;
  int m0 = mt * 128, n0 = nt * 128;

  // per-lane global source for direct-to-LDS staging (linear [128][64] LDS)
  int ls = lane >> 3;            // row within 8-row chunk
  int lc = (lane & 7) * 8;       // col element (16B chunk)
  const uint16_t* Abase = Ag + (size_t)(m0 + wid * 32 + ls) * 1024 + lc;
  const uint16_t* Bbase = Bg + (size_t)(n0 + wid * 32 + ls) * 1024 + lc;
  uint16_t* Alds = As + wid * 32 * 64;     // wave-uniform chunk base
  uint16_t* Blds = Bs + wid * 32 * 64;

  v4f acc[4][4];
  #pragma unroll
  for (int a = 0; a < 4; ++a)
    #pragma unroll
    for (int c = 0; c < 4; ++c) acc[a][c] = vzero();

  for (int kk = 0; kk < 1024; kk += 64){
    __syncthreads();                       // previous compute done before overwrite
    #pragma unroll
    for (int i = 0; i < 4; ++i){
      gld16(Abase + (size_t)(i * 8) * 1024 + kk, Alds + i * 8 * 64);
      gld16(Bbase + (size_t)(i * 8) * 1024 + kk, Blds + i * 8 * 64);
    }
    __syncthreads();                       // drains vmcnt(0): tiles visible
    #pragma unroll
    for (int kc = 0; kc < 2; ++kc){
      v8bf af[4], bfr[4];
      #pragma unroll
      for (int mi = 0; mi < 4; ++mi)
        af[mi] = *(const v8bf*)(As + (wr * 64 + mi * 16 + l15) * 64 + kc * 32 + lg * 8);
      #pragma unroll
      for (int nj = 0; nj < 4; ++nj)
        bfr[nj] = *(const v8bf*)(Bs + (wc * 64 + nj * 16 + l15) * 64 + kc * 32 + lg * 8);
      #pragma unroll
      for (int mi = 0; mi < 4; ++mi)
        #pragma unroll
        for (int nj = 0; nj < 4; ++nj)
          acc[mi][nj] = __builtin_amdgcn_mfma_f32_16x16x32_bf16(af[mi], bfr[nj], acc[mi][nj], 0, 0, 0);
    }
  }
  // ---- epilogue: stage C tile in LDS (stride 132), store vectorized ----
  __syncthreads();
  uint16_t* Ct = smem;
  #pragma unroll
  for (int nj = 0; nj < 4; ++nj){
    int n = n0 + wc * 64 + nj * 16 + l15;
    float bv_ = (n < 1024) ? qb[n] : (n < 2048) ? kb[n - 1024] : vb[n - 2048];
    #pragma unroll
    for (int mi = 0; mi < 4; ++mi)
      #pragma unroll
      for (int r = 0; r < 4; ++r){
        int ml = wr * 64 + mi * 16 + lg * 4 + r;
        Ct[ml * 132 + wc * 64 + nj * 16 + l15] = f2bf(acc[mi][nj][r] + bv_);
      }
  }
  __syncthreads();
  {
    int row = tid >> 1;
    int c0  = (tid & 1) * 64;
    uint16_t* gp = Cg + (size_t)(m0 + row) * 3072 + n0 + c0;
    const uint16_t* sp = Ct + row * 132 + c0;
    #pragma unroll
    for (int c = 0; c < 8; ++c)
      *(uint4*)(gp + c * 8) = *(const uint4*)(sp + c * 8);
  }
}

// ---------------- pass 1: column sums (balanced pair of j-tiles) ----------------
__global__ __launch_bounds__(256, 2)
void k_colsum(const uint16_t* __restrict__ QKVg, float* __restrict__ csum){
  __shared__ __align__(16) uint16_t Ka[64 * 72], KbS[64 * 72], Qs[64 * 72];
  __shared__ float colacc[128];
  int tid = threadIdx.x, lane = tid & 63, l15 = lane & 15, lg = lane >> 4, wid = tid >> 6;
  int wr = wid >> 1, wc = wid & 1;
  int bid = blockIdx.x, xcd = bid & 7, idx = bid >> 3;
  int bh = xcd * 8 + (idx & 7);
  int p4 = idx >> 3; int pr = (p4 < 4) ? p4 : 11 - p4;
  int b = bh >> 4, h = bh & 15;
  int jtA = pr, jtB = 15 - pr;
  const uint16_t* Qb = QKVg + (size_t)b * 1024 * 3072 + h * 64;
  const uint16_t* Kb = QKVg + (size_t)b * 1024 * 3072 + 1024 + h * 64;
  stage64(Ka,  Kb + (size_t)jtA * 64 * 3072, 3072, tid);
  stage64(KbS, Kb + (size_t)jtB * 64 * 3072, 3072, tid);
  if (tid < 128) colacc[tid] = 0.f;
  uint4 rq[2]; ld64(rq, Qb + (size_t)jtA * 64 * 3072, 3072, tid);
  float cpA[2] = {0.f, 0.f}, cpB[2] = {0.f, 0.f};
  for (int it = jtA; it < 16; ++it){
    __syncthreads();
    st64(Qs, rq, tid);
    __syncthreads();
    if (it < 15) ld64(rq, Qb + (size_t)(it + 1) * 64 * 3072, 3072, tid);
    bool doB = (it >= jtB);
    v4f sa[2][2], sb[2][2];
    #pragma unroll
    for (int a = 0; a < 2; ++a)
      #pragma unroll
      for (int c = 0; c < 2; ++c){ sa[a][c] = vzero(); sb[a][c] = vzero(); }
    #pragma unroll
    for (int kc = 0; kc < 2; ++kc){
      v8bf aq[2], k1[2], k2[2];
      #pragma unroll
      for (int mi = 0; mi < 2; ++mi)
        aq[mi] = *(const v8bf*)(Qs + (wr * 32 + mi * 16 + l15) * 72 + kc * 32 + lg * 8);
      #pragma unroll
      for (int nj = 0; nj < 2; ++nj)
        k1[nj] = *(const v8bf*)(Ka + (wc * 32 + nj * 16 + l15) * 72 + kc * 32 + lg * 8);
      #pragma unroll
      for (int mi = 0; mi < 2; ++mi)
        #pragma unroll
        for (int nj = 0; nj < 2; ++nj)
          sa[mi][nj] = __builtin_amdgcn_mfma_f32_16x16x32_bf16(aq[mi], k1[nj], sa[mi][nj], 0, 0, 0);
      if (doB){
        #pragma unroll
        for (int nj = 0; nj < 2; ++nj)
          k2[nj] = *(const v8bf*)(KbS + (wc * 32 + nj * 16 + l15) * 72 + kc * 32 + lg * 8);
        #pragma unroll
        for (int mi = 0; mi < 2; ++mi)
          #pragma unroll
          for (int nj = 0; nj < 2; ++nj)
            sb[mi][nj] = __builtin_amdgcn_mfma_f32_16x16x32_bf16(aq[mi], k2[nj], sb[mi][nj], 0, 0, 0);
      }
    }
    #pragma unroll
    for (int mi = 0; mi < 2; ++mi)
      #pragma unroll
      for (int nj = 0; nj < 2; ++nj)
        #pragma unroll
        for (int r = 0; r < 4; ++r){
          int il = wr * 32 + mi * 16 + lg * 4 + r;
          int jl = wc * 32 + nj * 16 + l15;
          if (it > jtA || il >= jl) cpA[nj] += __expf(sa[mi][nj][r] * 0.03125f);
          if (doB && (it > jtB || il >= jl)) cpB[nj] += __expf(sb[mi][nj][r] * 0.03125f);
        }
  }
  #pragma unroll
  for (int nj = 0; nj < 2; ++nj){
    float v = cpA[nj];
    v += __shfl_xor(v, 16, 64); v += __shfl_xor(v, 32, 64);
    if (lane < 16) atomicAdd(&colacc[wc * 32 + nj * 16 + l15], v);
    float w = cpB[nj];
    w += __shfl_xor(w, 16, 64); w += __shfl_xor(w, 32, 64);
    if (lane < 16) atomicAdd(&colacc[64 + wc * 32 + nj * 16 + l15], w);
  }
  __syncthreads();
  if (tid < 64)       csum[(size_t)bh * 1024 + jtA * 64 + tid] = colacc[tid];
  else if (tid < 128) csum[(size_t)bh * 1024 + jtB * 64 + (tid - 64)] = colacc[tid];
}

// ---------------- V' = V * mask/colsum, transposed to [bh][64 d][1024 j] ----------------
__global__ __launch_bounds__(256)
void k_vprep(const uint16_t* __restrict__ QKVg, const float* __restrict__ csum,
             const float* __restrict__ mask, uint16_t* __restrict__ Vp){
  __shared__ __align__(16) uint16_t Vs[128 * 72];
  __shared__ float scb[128];
  int tid = threadIdx.x;
  int bid = blockIdx.x, xcd = bid & 7, idx = bid >> 3;
  int bh = xcd * 8 + (idx & 7);
  int jt = idx >> 3;
  int b = bh >> 4, h = bh & 15;
  int j0 = jt * 128;
  stage64(Vs,           QKVg + ((size_t)(b * 1024 + j0)) * 3072 + 2048 + h * 64, 3072, tid);
  stage64(Vs + 64 * 72, QKVg + ((size_t)(b * 1024 + j0 + 64)) * 3072 + 2048 + h * 64, 3072, tid);
  if (tid < 128) scb[tid] = mask[b * 1024 + j0 + tid] / csum[(size_t)bh * 1024 + j0 + tid];
  __syncthreads();
  int d = tid >> 2, jc = (tid & 3) * 32;
  #pragma unroll
  for (int g8 = 0; g8 < 4; ++g8){
    union { uint16_t h[8]; uint4 v; } o;
    #pragma unroll
    for (int e = 0; e < 8; ++e){
      int j = jc + g8 * 8 + e;
      o.h[e] = f2bf(bf2f(Vs[j * 72 + d]) * scb[j]);
    }
    *(uint4*)(Vp + (size_t)bh * 65536 + (size_t)d * 1024 + j0 + jc + g8 * 8) = o.v;
  }
}

// ---------------- pass 2: O = exp(S) @ V' (balanced pair of i-tiles) ----------------
__global__ __launch_bounds__(256, 2)
void k_attnout(const uint16_t* __restrict__ QKVg, const uint16_t* __restrict__ Vp,
               float* __restrict__ out){
  __shared__ __align__(16) uint16_t Qs[128 * 72], Ks[64 * 72], Vt[64 * 72], Ps[128 * 72];
  int tid = threadIdx.x, lane = tid & 63, l15 = lane & 15, lg = lane >> 4, wid = tid >> 6;
  int wr = wid >> 1, wc = wid & 1;
  int bid = blockIdx.x, xcd = bid & 7, idx = bid >> 3;
  int bh = xcd * 8 + (idx & 7);
  int p4 = idx >> 3; int pr = (p4 < 4) ? p4 : 11 - p4;
  int b = bh >> 4, h = bh & 15;
  int itA = pr, itB = 15 - pr;
  const uint16_t* Qb = QKVg + (size_t)b * 1024 * 3072 + h * 64;
  const uint16_t* Kb = QKVg + (size_t)b * 1024 * 3072 + 1024 + h * 64;
  const uint16_t* Vb = Vp + (size_t)bh * 65536;
  stage64(Qs,           Qb + (size_t)itA * 64 * 3072, 3072, tid);
  stage64(Qs + 64 * 72, Qb + (size_t)itB * 64 * 3072, 3072, tid);
  uint4 rk[2], rv[2];
  ld64(rk, Kb, 3072, tid);
  ld64(rv, Vb, 1024, tid);
  v4f oacc[2][2][2];
  #pragma unroll
  for (int a = 0; a < 2; ++a)
    #pragma unroll
    for (int c = 0; c < 2; ++c)
      #pragma unroll
      for (int d = 0; d < 2; ++d) oacc[a][c][d] = vzero();

  for (int jt = 0; jt <= itB; ++jt){
    __syncthreads();
    st64(Ks, rk, tid);
    st64(Vt, rv, tid);
    __syncthreads();
    if (jt < itB){
      ld64(rk, Kb + (size_t)(jt + 1) * 64 * 3072, 3072, tid);
      ld64(rv, Vb + (jt + 1) * 64, 1024, tid);
    }
    #pragma unroll
    for (int half = 0; half < 2; ++half){
      int ith = half ? itB : itA;
      if (jt <= ith){
        v4f sacc[2][2];
        #pragma unroll
        for (int a = 0; a < 2; ++a)
          #pragma unroll
          for (int c = 0; c < 2; ++c) sacc[a][c] = vzero();
        #pragma unroll
        for (int kc = 0; kc < 2; ++kc){
          v8bf ak[2], aq[2];
          #pragma unroll
          for (int mj = 0; mj < 2; ++mj)
            ak[mj] = *(const v8bf*)(Ks + (wr * 32 + mj * 16 + l15) * 72 + kc * 32 + lg * 8);
          #pragma unroll
          for (int ni = 0; ni < 2; ++ni)
            aq[ni] = *(const v8bf*)(Qs + (half * 64 + wc * 32 + ni * 16 + l15) * 72 + kc * 32 + lg * 8);
          #pragma unroll
          for (int mj = 0; mj < 2; ++mj)
            #pragma unroll
            for (int ni = 0; ni < 2; ++ni)
              sacc[mj][ni] = __builtin_amdgcn_mfma_f32_16x16x32_bf16(ak[mj], aq[ni], sacc[mj][ni], 0, 0, 0);
        }
        bool diag = (jt == ith);
        #pragma unroll
        for (int mj = 0; mj < 2; ++mj)
          #pragma unroll
          for (int ni = 0; ni < 2; ++ni){
            int iL = wc * 32 + ni * 16 + l15;
            int jb = wr * 32 + mj * 16 + lg * 4;
            float e0 = (!diag || jb + 0 <= iL) ? __expf(sacc[mj][ni][0] * 0.03125f) : 0.f;
            float e1 = (!diag || jb + 1 <= iL) ? __expf(sacc[mj][ni][1] * 0.03125f) : 0.f;
            float e2 = (!diag || jb + 2 <= iL) ? __expf(sacc[mj][ni][2] * 0.03125f) : 0.f;
            float e3 = (!diag || jb + 3 <= iL) ? __expf(sacc[mj][ni][3] * 0.03125f) : 0.f;
            uint2 pk;
            pk.x = (uint32_t)f2bf(e0) | ((uint32_t)f2bf(e1) << 16);
            pk.y = (uint32_t)f2bf(e2) | ((uint32_t)f2bf(e3) << 16);
            *(uint2*)(Ps + (half * 64 + iL) * 72 + jb) = pk;
          }
      }
    }
    __syncthreads();
    #pragma unroll
    for (int half = 0; half < 2; ++half){
      int ith = half ? itB : itA;
      if (jt <= ith){
        #pragma unroll
        for (int kc = 0; kc < 2; ++kc){
          v8bf pa[2], vb_[2];
          #pragma unroll
          for (int mi = 0; mi < 2; ++mi)
            pa[mi] = *(const v8bf*)(Ps + (half * 64 + wr * 32 + mi * 16 + l15) * 72 + kc * 32 + lg * 8);
          #pragma unroll
          for (int nj = 0; nj < 2; ++nj)
            vb_[nj] = *(const v8bf*)(Vt + (wc * 32 + nj * 16 + l15) * 72 + kc * 32 + lg * 8);
          #pragma unroll
          for (int mi = 0; mi < 2; ++mi)
            #pragma unroll
            for (int nj = 0; nj < 2; ++nj)
              oacc[half][mi][nj] = __builtin_amdgcn_mfma_f32_16x16x32_bf16(pa[mi], vb_[nj], oacc[half][mi][nj], 0, 0, 0);
        }
      }
    }
  }
  #pragma unroll
  for (int half = 0; half < 2; ++half){
    int ith = half ? itB : itA;
    #pragma unroll
    for (int mi = 0; mi < 2; ++mi)
      #pragma unroll
      for (int nj = 0; nj < 2; ++nj)
        #pragma unroll
        for (int r = 0; r < 4; ++r){
          int ig = ith * 64 + wr * 32 + mi * 16 + lg * 4 + r;
          int d  = wc * 32 + nj * 16 + l15;
          out[((size_t)(b * 1024) + ig) * 1024 + h * 64 + d] = oacc[half][mi][nj][r];
        }
  }
}

extern "C" void kernel_launch(void* const* d_in, const int* in_sizes, int n_in,
                              void* d_out, int out_size, void* d_ws, size_t ws_size,
                              hipStream_t stream) {
  (void)in_sizes; (void)n_in; (void)out_size; (void)ws_size;
  const float* X    = (const float*)d_in[0];
  const float* mask = (const float*)d_in[1];
  const float* Wq   = (const float*)d_in[2];
  const float* bq   = (const float*)d_in[3];
  const float* Wk   = (const float*)d_in[4];
  const float* bk   = (const float*)d_in[5];
  const float* Wv   = (const float*)d_in[6];
  const float* bv   = (const float*)d_in[7];
  const float* Aq   = (const float*)d_in[8];
  const float* Bq   = (const float*)d_in[9];
  const float* Ak   = (const float*)d_in[10];
  const float* Bk   = (const float*)d_in[11];
  const float* Av   = (const float*)d_in[12];
  const float* Bv   = (const float*)d_in[13];
  float* out = (float*)d_out;

  uint16_t* Xb   = (uint16_t*)d_ws;                        // 8 MB
  uint16_t* Weff = Xb + (size_t)4096 * 1024;               // 6 MB  [3072][1024]
  uint16_t* QKV  = Weff + (size_t)3 * 1024 * 1024;         // 24 MB [4096][3072]
  uint16_t* Vp   = QKV + (size_t)4096 * 3072;              // 8 MB  [64][64][1024]
  float*    csum = (float*)(Vp + (size_t)64 * 64 * 1024);  // 256 KB

  k_xcast<<<2048, 256, 0, stream>>>(X, Xb);
  k_weff<<<dim3(4096, 3), 256, 0, stream>>>(Wq, Aq, Bq, Wk, Ak, Bk, Wv, Av, Bv, Weff);
  k_gemm<<<768, 256, 0, stream>>>(Xb, Weff, bq, bk, bv, QKV);
  k_colsum<<<512, 256, 0, stream>>>(QKV, csum);
  k_vprep<<<512, 256, 0, stream>>>(QKV, csum, mask, Vp);
  k_attnout<<<512, 256, 0, stream>>>(QKV, Vp, out);
}

// Round 5
// 128.760 us; speedup vs baseline: 1.6202x; 1.0135x over previous
//
#include <hip/hip_runtime.h>
#include <stdint.h>

typedef __bf16 v8bf __attribute__((ext_vector_type(8)));
typedef float  v4f  __attribute__((ext_vector_type(4)));

__device__ __forceinline__ uint16_t f2bf(float f){
  union { float f; uint32_t u; } v; v.f = f;
  uint32_t r = v.u + 0x7FFFu + ((v.u >> 16) & 1u);
  return (uint16_t)(r >> 16);
}
__device__ __forceinline__ float bf2f(uint16_t u){
  union { uint32_t u; float f; } v; v.u = ((uint32_t)u) << 16; return v.f;
}
__device__ __forceinline__ v4f vzero(){ v4f z = {0.f,0.f,0.f,0.f}; return z; }

// async global->LDS, 16B per lane; LDS dest is wave-uniform base + lane*16
__device__ __forceinline__ void gld16(const uint16_t* __restrict__ g, uint16_t* l){
  __builtin_amdgcn_global_load_lds((const __attribute__((address_space(1))) void*)g,
                                   (__attribute__((address_space(3))) void*)l, 16, 0, 0);
}

// ---- 64x64 bf16 tile staging (LDS row stride 72) ---- (attn kernels)
__device__ __forceinline__ void ld64(uint4 r[2], const uint16_t* __restrict__ g, int ldg, int tid){
  int row = tid >> 2, c = (tid & 3) * 16;
  r[0] = *(const uint4*)(g + (size_t)row * ldg + c);
  r[1] = *(const uint4*)(g + (size_t)row * ldg + c + 8);
}
__device__ __forceinline__ void st64(uint16_t* __restrict__ s, const uint4 r[2], int tid){
  int row = tid >> 2, c = (tid & 3) * 16;
  *(uint4*)(s + row * 72 + c) = r[0];
  *(uint4*)(s + row * 72 + c + 8) = r[1];
}
__device__ __forceinline__ void stage64(uint16_t* s, const uint16_t* g, int ldg, int tid){
  uint4 r[2]; ld64(r, g, ldg, tid); st64(s, r, tid);
}

// ---------------- prep ----------------
__global__ void k_xcast(const float* __restrict__ X, uint16_t* __restrict__ Xb){
  int i = (blockIdx.x * 256 + threadIdx.x) * 8;
  float4 a = *(const float4*)(X + i);
  float4 b = *(const float4*)(X + i + 4);
  union { uint16_t h[8]; uint4 v; } o;
  o.h[0]=f2bf(a.x); o.h[1]=f2bf(a.y); o.h[2]=f2bf(a.z); o.h[3]=f2bf(a.w);
  o.h[4]=f2bf(b.x); o.h[5]=f2bf(b.y); o.h[6]=f2bf(b.z); o.h[7]=f2bf(b.w);
  *(uint4*)(Xb + i) = o.v;
}

__global__ void k_zero(float* __restrict__ p){
  int i = (blockIdx.x * 256 + threadIdx.x) * 4;
  *(float4*)(p + i) = make_float4(0.f, 0.f, 0.f, 0.f);
}

__global__ void k_weff(const float* __restrict__ Wq, const float* __restrict__ Aq, const float* __restrict__ Bq,
                       const float* __restrict__ Wk, const float* __restrict__ Ak, const float* __restrict__ Bk,
                       const float* __restrict__ Wv, const float* __restrict__ Av, const float* __restrict__ Bv,
                       uint16_t* __restrict__ Wo){
  int y = blockIdx.y;
  const float* W  = (y == 0) ? Wq : (y == 1) ? Wk : Wv;
  const float* A  = (y == 0) ? Aq : (y == 1) ? Ak : Av;
  const float* Bm = (y == 0) ? Bq : (y == 1) ? Bk : Bv;
  int idx = blockIdx.x * 256 + threadIdx.x;
  int f = idx >> 10, k = idx & 1023;
  float acc = W[idx];
  #pragma unroll
  for (int r = 0; r < 16; ++r) acc += Bm[f * 16 + r] * A[r * 1024 + k];
  Wo[(size_t)y * 1048576 + idx] = f2bf(acc);
}

// ---------------- fused QKV projection GEMM (m97 structure + XOR swizzle) ----------------
// C[4096,3072] = Xb[4096,1024] @ Weff[3072,1024]^T + bias
// LDS tile [128][64]; 16B chunk c of row r stored at physical chunk c ^ (r&7).
// global_load_lds writes linearly -> global SOURCE is inverse-swizzled per lane (rule #21).
__global__ __launch_bounds__(256, 4)
void k_gemm(const uint16_t* __restrict__ Ag, const uint16_t* __restrict__ Bg,
            const float* __restrict__ qb, const float* __restrict__ kb,
            const float* __restrict__ vb, uint16_t* __restrict__ Cg){
  __shared__ __align__(16) uint16_t smem[16896];   // As[8192] Bs[8192]; reused as Ct[128*132]
  uint16_t* As = smem;
  uint16_t* Bs = smem + 8192;
  int tid = threadIdx.x, lane = tid & 63, wid = tid >> 6;
  int l15 = lane & 15, lg = lane >> 4;
  int wr = wid >> 1, wc = wid & 1;
  int bid = blockIdx.x, xcd = bid & 7, idx = bid >> 3;
  int nb = xcd * 96 + idx;                 // 768 blocks, 96/XCD chunk
  int mt = nb / 24, nt = nb - mt * 24;
  int m0 = mt * 128, n0 = nt * 128;

  // staging: lane lr=row within 8-row group, source col chunk pre-swizzled
  int lr  = lane >> 3;                          // 0..7
  int lcs = (((lane & 7) ^ lr)) * 8;            // inverse-swizzled global col (elems)
  const uint16_t* Abase = Ag + (size_t)(m0 + wid * 32 + lr) * 1024 + lcs;
  const uint16_t* Bbase = Bg + (size_t)(n0 + wid * 32 + lr) * 1024 + lcs;
  uint16_t* Alds = As + wid * 32 * 64;          // wave-uniform chunk base
  uint16_t* Blds = Bs + wid * 32 * 64;

  int sw = l15 & 7;                             // read-side swizzle key (row&7)

  v4f acc[4][4];
  #pragma unroll
  for (int a = 0; a < 4; ++a)
    #pragma unroll
    for (int c = 0; c < 4; ++c) acc[a][c] = vzero();

  for (int kk = 0; kk < 1024; kk += 64){
    __syncthreads();                       // previous compute done before overwrite
    #pragma unroll
    for (int i = 0; i < 4; ++i){
      gld16(Abase + (size_t)(i * 8) * 1024 + kk, Alds + i * 8 * 64);
      gld16(Bbase + (size_t)(i * 8) * 1024 + kk, Blds + i * 8 * 64);
    }
    __syncthreads();                       // drains vmcnt(0): tiles visible
    #pragma unroll
    for (int kc = 0; kc < 2; ++kc){
      v8bf af[4], bfr[4];
      int cs = ((kc * 4 + lg) ^ sw) * 8;   // physical chunk offset (elems)
      #pragma unroll
      for (int mi = 0; mi < 4; ++mi)
        af[mi] = *(const v8bf*)(As + (wr * 64 + mi * 16 + l15) * 64 + cs);
      #pragma unroll
      for (int nj = 0; nj < 4; ++nj)
        bfr[nj] = *(const v8bf*)(Bs + (wc * 64 + nj * 16 + l15) * 64 + cs);
      #pragma unroll
      for (int mi = 0; mi < 4; ++mi)
        #pragma unroll
        for (int nj = 0; nj < 4; ++nj)
          acc[mi][nj] = __builtin_amdgcn_mfma_f32_16x16x32_bf16(af[mi], bfr[nj], acc[mi][nj], 0, 0, 0);
    }
  }
  // ---- epilogue: stage C tile in LDS (stride 132), store vectorized ----
  __syncthreads();
  uint16_t* Ct = smem;
  #pragma unroll
  for (int nj = 0; nj < 4; ++nj){
    int n = n0 + wc * 64 + nj * 16 + l15;
    float bv_ = (n < 1024) ? qb[n] : (n < 2048) ? kb[n - 1024] : vb[n - 2048];
    #pragma unroll
    for (int mi = 0; mi < 4; ++mi)
      #pragma unroll
      for (int r = 0; r < 4; ++r){
        int ml = wr * 64 + mi * 16 + lg * 4 + r;
        Ct[ml * 132 + wc * 64 + nj * 16 + l15] = f2bf(acc[mi][nj][r] + bv_);
      }
  }
  __syncthreads();
  {
    int row = tid >> 1;
    int c0  = (tid & 1) * 64;
    uint16_t* gp = Cg + (size_t)(m0 + row) * 3072 + n0 + c0;
    const uint16_t* sp = Ct + row * 132 + c0;
    #pragma unroll
    for (int c = 0; c < 8; ++c)
      *(uint4*)(gp + c * 8) = *(const uint4*)(sp + c * 8);
  }
}

// ---------------- pass 1: column sums (pair of j-tiles, i-range split by parity) ----------------
// grid 1024: (xcd, bh, pair, phase); atomicAdd partials into pre-zeroed csum
__global__ __launch_bounds__(256, 4)
void k_colsum(const uint16_t* __restrict__ QKVg, float* __restrict__ csum){
  __shared__ __align__(16) uint16_t Ka[64 * 72], KbS[64 * 72], Qs[64 * 72];
  __shared__ float colacc[128];
  int tid = threadIdx.x, lane = tid & 63, l15 = lane & 15, lg = lane >> 4, wid = tid >> 6;
  int wr = wid >> 1, wc = wid & 1;
  int bid = blockIdx.x, xcd = bid & 7, idx = bid >> 3;
  int bh = xcd * 8 + (idx & 7);
  int rest = idx >> 3;                 // 0..15
  int pr = rest & 7, ph = rest >> 3;   // pair 0..7, phase 0..1
  int b = bh >> 4, h = bh & 15;
  int jtA = pr, jtB = 15 - pr;
  const uint16_t* Qb = QKVg + (size_t)b * 1024 * 3072 + h * 64;
  const uint16_t* Kb = QKVg + (size_t)b * 1024 * 3072 + 1024 + h * 64;
  stage64(Ka,  Kb + (size_t)jtA * 64 * 3072, 3072, tid);
  stage64(KbS, Kb + (size_t)jtB * 64 * 3072, 3072, tid);
  if (tid < 128) colacc[tid] = 0.f;
  int it0 = jtA + ph;
  uint4 rq[2]; ld64(rq, Qb + (size_t)it0 * 64 * 3072, 3072, tid);
  float cpA[2] = {0.f, 0.f}, cpB[2] = {0.f, 0.f};
  for (int it = it0; it < 16; it += 2){
    __syncthreads();
    st64(Qs, rq, tid);
    __syncthreads();
    if (it + 2 < 16) ld64(rq, Qb + (size_t)(it + 2) * 64 * 3072, 3072, tid);
    bool doB = (it >= jtB);
    v4f sa[2][2], sb[2][2];
    #pragma unroll
    for (int a = 0; a < 2; ++a)
      #pragma unroll
      for (int c = 0; c < 2; ++c){ sa[a][c] = vzero(); sb[a][c] = vzero(); }
    #pragma unroll
    for (int kc = 0; kc < 2; ++kc){
      v8bf aq[2], k1[2], k2[2];
      #pragma unroll
      for (int mi = 0; mi < 2; ++mi)
        aq[mi] = *(const v8bf*)(Qs + (wr * 32 + mi * 16 + l15) * 72 + kc * 32 + lg * 8);
      #pragma unroll
      for (int nj = 0; nj < 2; ++nj)
        k1[nj] = *(const v8bf*)(Ka + (wc * 32 + nj * 16 + l15) * 72 + kc * 32 + lg * 8);
      #pragma unroll
      for (int mi = 0; mi < 2; ++mi)
        #pragma unroll
        for (int nj = 0; nj < 2; ++nj)
          sa[mi][nj] = __builtin_amdgcn_mfma_f32_16x16x32_bf16(aq[mi], k1[nj], sa[mi][nj], 0, 0, 0);
      if (doB){
        #pragma unroll
        for (int nj = 0; nj < 2; ++nj)
          k2[nj] = *(const v8bf*)(KbS + (wc * 32 + nj * 16 + l15) * 72 + kc * 32 + lg * 8);
        #pragma unroll
        for (int mi = 0; mi < 2; ++mi)
          #pragma unroll
          for (int nj = 0; nj < 2; ++nj)
            sb[mi][nj] = __builtin_amdgcn_mfma_f32_16x16x32_bf16(aq[mi], k2[nj], sb[mi][nj], 0, 0, 0);
      }
    }
    #pragma unroll
    for (int mi = 0; mi < 2; ++mi)
      #pragma unroll
      for (int nj = 0; nj < 2; ++nj)
        #pragma unroll
        for (int r = 0; r < 4; ++r){
          int il = wr * 32 + mi * 16 + lg * 4 + r;
          int jl = wc * 32 + nj * 16 + l15;
          if (it > jtA || il >= jl) cpA[nj] += __expf(sa[mi][nj][r] * 0.03125f);
          if (doB && (it > jtB || il >= jl)) cpB[nj] += __expf(sb[mi][nj][r] * 0.03125f);
        }
  }
  #pragma unroll
  for (int nj = 0; nj < 2; ++nj){
    float v = cpA[nj];
    v += __shfl_xor(v, 16, 64); v += __shfl_xor(v, 32, 64);
    if (lane < 16) atomicAdd(&colacc[wc * 32 + nj * 16 + l15], v);
    float w = cpB[nj];
    w += __shfl_xor(w, 16, 64); w += __shfl_xor(w, 32, 64);
    if (lane < 16) atomicAdd(&colacc[64 + wc * 32 + nj * 16 + l15], w);
  }
  __syncthreads();
  if (tid < 64)       atomicAdd(&csum[(size_t)bh * 1024 + jtA * 64 + tid], colacc[tid]);
  else if (tid < 128) atomicAdd(&csum[(size_t)bh * 1024 + jtB * 64 + (tid - 64)], colacc[tid]);
}

// ---------------- V' = V * mask/colsum, transposed to [bh][64 d][1024 j] ----------------
__global__ __launch_bounds__(256)
void k_vprep(const uint16_t* __restrict__ QKVg, const float* __restrict__ csum,
             const float* __restrict__ mask, uint16_t* __restrict__ Vp){
  __shared__ __align__(16) uint16_t Vs[128 * 72];
  __shared__ float scb[128];
  int tid = threadIdx.x;
  int bid = blockIdx.x, xcd = bid & 7, idx = bid >> 3;
  int bh = xcd * 8 + (idx & 7);
  int jt = idx >> 3;
  int b = bh >> 4, h = bh & 15;
  int j0 = jt * 128;
  stage64(Vs,           QKVg + ((size_t)(b * 1024 + j0)) * 3072 + 2048 + h * 64, 3072, tid);
  stage64(Vs + 64 * 72, QKVg + ((size_t)(b * 1024 + j0 + 64)) * 3072 + 2048 + h * 64, 3072, tid);
  if (tid < 128) scb[tid] = mask[b * 1024 + j0 + tid] / csum[(size_t)bh * 1024 + j0 + tid];
  __syncthreads();
  int d = tid >> 2, jc = (tid & 3) * 32;
  #pragma unroll
  for (int g8 = 0; g8 < 4; ++g8){
    union { uint16_t h[8]; uint4 v; } o;
    #pragma unroll
    for (int e = 0; e < 8; ++e){
      int j = jc + g8 * 8 + e;
      o.h[e] = f2bf(bf2f(Vs[j * 72 + d]) * scb[j]);
    }
    *(uint4*)(Vp + (size_t)bh * 65536 + (size_t)d * 1024 + j0 + jc + g8 * 8) = o.v;
  }
}

// ---------------- pass 2: O = exp(S) @ V' (balanced pair of i-tiles) ----------------
__global__ __launch_bounds__(256, 2)
void k_attnout(const uint16_t* __restrict__ QKVg, const uint16_t* __restrict__ Vp,
               float* __restrict__ out){
  __shared__ __align__(16) uint16_t Qs[128 * 72], Ks[64 * 72], Vt[64 * 72], Ps[128 * 72];
  int tid = threadIdx.x, lane = tid & 63, l15 = lane & 15, lg = lane >> 4, wid = tid >> 6;
  int wr = wid >> 1, wc = wid & 1;
  int bid = blockIdx.x, xcd = bid & 7, idx = bid >> 3;
  int bh = xcd * 8 + (idx & 7);
  int p4 = idx >> 3; int pr = (p4 < 4) ? p4 : 11 - p4;
  int b = bh >> 4, h = bh & 15;
  int itA = pr, itB = 15 - pr;
  const uint16_t* Qb = QKVg + (size_t)b * 1024 * 3072 + h * 64;
  const uint16_t* Kb = QKVg + (size_t)b * 1024 * 3072 + 1024 + h * 64;
  const uint16_t* Vb = Vp + (size_t)bh * 65536;
  stage64(Qs,           Qb + (size_t)itA * 64 * 3072, 3072, tid);
  stage64(Qs + 64 * 72, Qb + (size_t)itB * 64 * 3072, 3072, tid);
  uint4 rk[2], rv[2];
  ld64(rk, Kb, 3072, tid);
  ld64(rv, Vb, 1024, tid);
  v4f oacc[2][2][2];
  #pragma unroll
  for (int a = 0; a < 2; ++a)
    #pragma unroll
    for (int c = 0; c < 2; ++c)
      #pragma unroll
      for (int d = 0; d < 2; ++d) oacc[a][c][d] = vzero();

  for (int jt = 0; jt <= itB; ++jt){
    __syncthreads();
    st64(Ks, rk, tid);
    st64(Vt, rv, tid);
    __syncthreads();
    if (jt < itB){
      ld64(rk, Kb + (size_t)(jt + 1) * 64 * 3072, 3072, tid);
      ld64(rv, Vb + (jt + 1) * 64, 1024, tid);
    }
    #pragma unroll
    for (int half = 0; half < 2; ++half){
      int ith = half ? itB : itA;
      if (jt <= ith){
        v4f sacc[2][2];
        #pragma unroll
        for (int a = 0; a < 2; ++a)
          #pragma unroll
          for (int c = 0; c < 2; ++c) sacc[a][c] = vzero();
        #pragma unroll
        for (int kc = 0; kc < 2; ++kc){
          v8bf ak[2], aq[2];
          #pragma unroll
          for (int mj = 0; mj < 2; ++mj)
            ak[mj] = *(const v8bf*)(Ks + (wr * 32 + mj * 16 + l15) * 72 + kc * 32 + lg * 8);
          #pragma unroll
          for (int ni = 0; ni < 2; ++ni)
            aq[ni] = *(const v8bf*)(Qs + (half * 64 + wc * 32 + ni * 16 + l15) * 72 + kc * 32 + lg * 8);
          #pragma unroll
          for (int mj = 0; mj < 2; ++mj)
            #pragma unroll
            for (int ni = 0; ni < 2; ++ni)
              sacc[mj][ni] = __builtin_amdgcn_mfma_f32_16x16x32_bf16(ak[mj], aq[ni], sacc[mj][ni], 0, 0, 0);
        }
        bool diag = (jt == ith);
        #pragma unroll
        for (int mj = 0; mj < 2; ++mj)
          #pragma unroll
          for (int ni = 0; ni < 2; ++ni){
            int iL = wc * 32 + ni * 16 + l15;
            int jb = wr * 32 + mj * 16 + lg * 4;
            float e0 = (!diag || jb + 0 <= iL) ? __expf(sacc[mj][ni][0] * 0.03125f) : 0.f;
            float e1 = (!diag || jb + 1 <= iL) ? __expf(sacc[mj][ni][1] * 0.03125f) : 0.f;
            float e2 = (!diag || jb + 2 <= iL) ? __expf(sacc[mj][ni][2] * 0.03125f) : 0.f;
            float e3 = (!diag || jb + 3 <= iL) ? __expf(sacc[mj][ni][3] * 0.03125f) : 0.f;
            uint2 pk;
            pk.x = (uint32_t)f2bf(e0) | ((uint32_t)f2bf(e1) << 16);
            pk.y = (uint32_t)f2bf(e2) | ((uint32_t)f2bf(e3) << 16);
            *(uint2*)(Ps + (half * 64 + iL) * 72 + jb) = pk;
          }
      }
    }
    __syncthreads();
    #pragma unroll
    for (int half = 0; half < 2; ++half){
      int ith = half ? itB : itA;
      if (jt <= ith){
        #pragma unroll
        for (int kc = 0; kc < 2; ++kc){
          v8bf pa[2], vb_[2];
          #pragma unroll
          for (int mi = 0; mi < 2; ++mi)
            pa[mi] = *(const v8bf*)(Ps + (half * 64 + wr * 32 + mi * 16 + l15) * 72 + kc * 32 + lg * 8);
          #pragma unroll
          for (int nj = 0; nj < 2; ++nj)
            vb_[nj] = *(const v8bf*)(Vt + (wc * 32 + nj * 16 + l15) * 72 + kc * 32 + lg * 8);
          #pragma unroll
          for (int mi = 0; mi < 2; ++mi)
            #pragma unroll
            for (int nj = 0; nj < 2; ++nj)
              oacc[half][mi][nj] = __builtin_amdgcn_mfma_f32_16x16x32_bf16(pa[mi], vb_[nj], oacc[half][mi][nj], 0, 0, 0);
        }
      }
    }
  }
  #pragma unroll
  for (int half = 0; half < 2; ++half){
    int ith = half ? itB : itA;
    #pragma unroll
    for (int mi = 0; mi < 2; ++mi)
      #pragma unroll
      for (int nj = 0; nj < 2; ++nj)
        #pragma unroll
        for (int r = 0; r < 4; ++r){
          int ig = ith * 64 + wr * 32 + mi * 16 + lg * 4 + r;
          int d  = wc * 32 + nj * 16 + l15;
          out[((size_t)(b * 1024) + ig) * 1024 + h * 64 + d] = oacc[half][mi][nj][r];
        }
  }
}

extern "C" void kernel_launch(void* const* d_in, const int* in_sizes, int n_in,
                              void* d_out, int out_size, void* d_ws, size_t ws_size,
                              hipStream_t stream) {
  (void)in_sizes; (void)n_in; (void)out_size; (void)ws_size;
  const float* X    = (const float*)d_in[0];
  const float* mask = (const float*)d_in[1];
  const float* Wq   = (const float*)d_in[2];
  const float* bq   = (const float*)d_in[3];
  const float* Wk   = (const float*)d_in[4];
  const float* bk   = (const float*)d_in[5];
  const float* Wv   = (const float*)d_in[6];
  const float* bv   = (const float*)d_in[7];
  const float* Aq   = (const float*)d_in[8];
  const float* Bq   = (const float*)d_in[9];
  const float* Ak   = (const float*)d_in[10];
  const float* Bk   = (const float*)d_in[11];
  const float* Av   = (const float*)d_in[12];
  const float* Bv   = (const float*)d_in[13];
  float* out = (float*)d_out;

  uint16_t* Xb   = (uint16_t*)d_ws;                        // 8 MB
  uint16_t* Weff = Xb + (size_t)4096 * 1024;               // 6 MB  [3072][1024]
  uint16_t* QKV  = Weff + (size_t)3 * 1024 * 1024;         // 24 MB [4096][3072]
  uint16_t* Vp   = QKV + (size_t)4096 * 3072;              // 8 MB  [64][64][1024]
  float*    csum = (float*)(Vp + (size_t)64 * 64 * 1024);  // 256 KB

  k_xcast<<<2048, 256, 0, stream>>>(X, Xb);
  k_zero<<<64, 256, 0, stream>>>(csum);
  k_weff<<<dim3(4096, 3), 256, 0, stream>>>(Wq, Aq, Bq, Wk, Ak, Bk, Wv, Av, Bv, Weff);
  k_gemm<<<768, 256, 0, stream>>>(Xb, Weff, bq, bk, bv, QKV);
  k_colsum<<<1024, 256, 0, stream>>>(QKV, csum);
  k_vprep<<<512, 256, 0, stream>>>(QKV, csum, mask, Vp);
  k_attnout<<<512, 256, 0, stream>>>(QKV, Vp, out);
}

// Round 6
// 128.090 us; speedup vs baseline: 1.6286x; 1.0052x over previous
//
#include <hip/hip_runtime.h>
#include <stdint.h>

typedef __bf16 v8bf __attribute__((ext_vector_type(8)));
typedef float  v4f  __attribute__((ext_vector_type(4)));

__device__ __forceinline__ uint16_t f2bf(float f){
  union { float f; uint32_t u; } v; v.f = f;
  uint32_t r = v.u + 0x7FFFu + ((v.u >> 16) & 1u);
  return (uint16_t)(r >> 16);
}
__device__ __forceinline__ float bf2f(uint16_t u){
  union { uint32_t u; float f; } v; v.u = ((uint32_t)u) << 16; return v.f;
}
__device__ __forceinline__ v4f vzero(){ v4f z = {0.f,0.f,0.f,0.f}; return z; }

// async global->LDS, 16B per lane; LDS dest is wave-uniform base + lane*16
__device__ __forceinline__ void gld16(const uint16_t* __restrict__ g, uint16_t* l){
  __builtin_amdgcn_global_load_lds((const __attribute__((address_space(1))) void*)g,
                                   (__attribute__((address_space(3))) void*)l, 16, 0, 0);
}

// ---- 64x64 bf16 tile staging, LDS row stride 72 (colsum/vprep) ----
__device__ __forceinline__ void ld64(uint4 r[2], const uint16_t* __restrict__ g, int ldg, int tid){
  int row = tid >> 2, c = (tid & 3) * 16;
  r[0] = *(const uint4*)(g + (size_t)row * ldg + c);
  r[1] = *(const uint4*)(g + (size_t)row * ldg + c + 8);
}
__device__ __forceinline__ void st64(uint16_t* __restrict__ s, const uint4 r[2], int tid){
  int row = tid >> 2, c = (tid & 3) * 16;
  *(uint4*)(s + row * 72 + c) = r[0];
  *(uint4*)(s + row * 72 + c + 8) = r[1];
}
__device__ __forceinline__ void stage64(uint16_t* s, const uint16_t* g, int ldg, int tid){
  uint4 r[2]; ld64(r, g, ldg, tid); st64(s, r, tid);
}

// ---- 64x64 bf16 tile staging, LINEAR stride 64 + chunk-XOR swizzle (attnout) ----
// logical 16B chunk c of row r lives at physical chunk c ^ (r&7)
__device__ __forceinline__ void st64s(uint16_t* __restrict__ s, const uint4 r[2], int tid){
  int row = tid >> 2, c0 = (tid & 3) * 2, sw = row & 7;
  *(uint4*)(s + row * 64 + ((c0 ^ sw) * 8))       = r[0];
  *(uint4*)(s + row * 64 + (((c0 + 1) ^ sw) * 8)) = r[1];
}
__device__ __forceinline__ void stage64s(uint16_t* s, const uint16_t* g, int ldg, int tid){
  uint4 r[2]; ld64(r, g, ldg, tid); st64s(s, r, tid);
}

// ---------------- prep ----------------
__global__ void k_xcast(const float* __restrict__ X, uint16_t* __restrict__ Xb){
  int i = (blockIdx.x * 256 + threadIdx.x) * 8;
  float4 a = *(const float4*)(X + i);
  float4 b = *(const float4*)(X + i + 4);
  union { uint16_t h[8]; uint4 v; } o;
  o.h[0]=f2bf(a.x); o.h[1]=f2bf(a.y); o.h[2]=f2bf(a.z); o.h[3]=f2bf(a.w);
  o.h[4]=f2bf(b.x); o.h[5]=f2bf(b.y); o.h[6]=f2bf(b.z); o.h[7]=f2bf(b.w);
  *(uint4*)(Xb + i) = o.v;
}

__global__ void k_zero(float* __restrict__ p){
  int i = (blockIdx.x * 256 + threadIdx.x) * 4;
  *(float4*)(p + i) = make_float4(0.f, 0.f, 0.f, 0.f);
}

__global__ void k_weff(const float* __restrict__ Wq, const float* __restrict__ Aq, const float* __restrict__ Bq,
                       const float* __restrict__ Wk, const float* __restrict__ Ak, const float* __restrict__ Bk,
                       const float* __restrict__ Wv, const float* __restrict__ Av, const float* __restrict__ Bv,
                       uint16_t* __restrict__ Wo){
  int y = blockIdx.y;
  const float* W  = (y == 0) ? Wq : (y == 1) ? Wk : Wv;
  const float* A  = (y == 0) ? Aq : (y == 1) ? Ak : Av;
  const float* Bm = (y == 0) ? Bq : (y == 1) ? Bk : Bv;
  int idx = blockIdx.x * 256 + threadIdx.x;
  int f = idx >> 10, k = idx & 1023;
  float acc = W[idx];
  #pragma unroll
  for (int r = 0; r < 16; ++r) acc += Bm[f * 16 + r] * A[r * 1024 + k];
  Wo[(size_t)y * 1048576 + idx] = f2bf(acc);
}

// ---------------- fused QKV projection GEMM (m97 structure + XOR swizzle) ----------------
__global__ __launch_bounds__(256, 4)
void k_gemm(const uint16_t* __restrict__ Ag, const uint16_t* __restrict__ Bg,
            const float* __restrict__ qb, const float* __restrict__ kb,
            const float* __restrict__ vb, uint16_t* __restrict__ Cg){
  __shared__ __align__(16) uint16_t smem[16896];   // As[8192] Bs[8192]; reused as Ct[128*132]
  uint16_t* As = smem;
  uint16_t* Bs = smem + 8192;
  int tid = threadIdx.x, lane = tid & 63, wid = tid >> 6;
  int l15 = lane & 15, lg = lane >> 4;
  int wr = wid >> 1, wc = wid & 1;
  int bid = blockIdx.x, xcd = bid & 7, idx = bid >> 3;
  int nb = xcd * 96 + idx;                 // 768 blocks, 96/XCD chunk
  int mt = nb / 24, nt = nb - mt * 24;
  int m0 = mt * 128, n0 = nt * 128;

  int lr  = lane >> 3;                          // 0..7
  int lcs = (((lane & 7) ^ lr)) * 8;            // inverse-swizzled global col (elems)
  const uint16_t* Abase = Ag + (size_t)(m0 + wid * 32 + lr) * 1024 + lcs;
  const uint16_t* Bbase = Bg + (size_t)(n0 + wid * 32 + lr) * 1024 + lcs;
  uint16_t* Alds = As + wid * 32 * 64;
  uint16_t* Blds = Bs + wid * 32 * 64;

  int sw = l15 & 7;

  v4f acc[4][4];
  #pragma unroll
  for (int a = 0; a < 4; ++a)
    #pragma unroll
    for (int c = 0; c < 4; ++c) acc[a][c] = vzero();

  for (int kk = 0; kk < 1024; kk += 64){
    __syncthreads();
    #pragma unroll
    for (int i = 0; i < 4; ++i){
      gld16(Abase + (size_t)(i * 8) * 1024 + kk, Alds + i * 8 * 64);
      gld16(Bbase + (size_t)(i * 8) * 1024 + kk, Blds + i * 8 * 64);
    }
    __syncthreads();
    #pragma unroll
    for (int kc = 0; kc < 2; ++kc){
      v8bf af[4], bfr[4];
      int cs = ((kc * 4 + lg) ^ sw) * 8;
      #pragma unroll
      for (int mi = 0; mi < 4; ++mi)
        af[mi] = *(const v8bf*)(As + (wr * 64 + mi * 16 + l15) * 64 + cs);
      #pragma unroll
      for (int nj = 0; nj < 4; ++nj)
        bfr[nj] = *(const v8bf*)(Bs + (wc * 64 + nj * 16 + l15) * 64 + cs);
      #pragma unroll
      for (int mi = 0; mi < 4; ++mi)
        #pragma unroll
        for (int nj = 0; nj < 4; ++nj)
          acc[mi][nj] = __builtin_amdgcn_mfma_f32_16x16x32_bf16(af[mi], bfr[nj], acc[mi][nj], 0, 0, 0);
    }
  }
  __syncthreads();
  uint16_t* Ct = smem;
  #pragma unroll
  for (int nj = 0; nj < 4; ++nj){
    int n = n0 + wc * 64 + nj * 16 + l15;
    float bv_ = (n < 1024) ? qb[n] : (n < 2048) ? kb[n - 1024] : vb[n - 2048];
    #pragma unroll
    for (int mi = 0; mi < 4; ++mi)
      #pragma unroll
      for (int r = 0; r < 4; ++r){
        int ml = wr * 64 + mi * 16 + lg * 4 + r;
        Ct[ml * 132 + wc * 64 + nj * 16 + l15] = f2bf(acc[mi][nj][r] + bv_);
      }
  }
  __syncthreads();
  {
    int row = tid >> 1;
    int c0  = (tid & 1) * 64;
    uint16_t* gp = Cg + (size_t)(m0 + row) * 3072 + n0 + c0;
    const uint16_t* sp = Ct + row * 132 + c0;
    #pragma unroll
    for (int c = 0; c < 8; ++c)
      *(uint4*)(gp + c * 8) = *(const uint4*)(sp + c * 8);
  }
}

// ---------------- pass 1: column sums (pair of j-tiles, i-range split by parity) ----------------
__global__ __launch_bounds__(256, 4)
void k_colsum(const uint16_t* __restrict__ QKVg, float* __restrict__ csum){
  __shared__ __align__(16) uint16_t Ka[64 * 72], KbS[64 * 72], Qs[64 * 72];
  __shared__ float colacc[128];
  int tid = threadIdx.x, lane = tid & 63, l15 = lane & 15, lg = lane >> 4, wid = tid >> 6;
  int wr = wid >> 1, wc = wid & 1;
  int bid = blockIdx.x, xcd = bid & 7, idx = bid >> 3;
  int bh = xcd * 8 + (idx & 7);
  int rest = idx >> 3;
  int pr = rest & 7, ph = rest >> 3;
  int b = bh >> 4, h = bh & 15;
  int jtA = pr, jtB = 15 - pr;
  const uint16_t* Qb = QKVg + (size_t)b * 1024 * 3072 + h * 64;
  const uint16_t* Kb = QKVg + (size_t)b * 1024 * 3072 + 1024 + h * 64;
  stage64(Ka,  Kb + (size_t)jtA * 64 * 3072, 3072, tid);
  stage64(KbS, Kb + (size_t)jtB * 64 * 3072, 3072, tid);
  if (tid < 128) colacc[tid] = 0.f;
  int it0 = jtA + ph;
  uint4 rq[2]; ld64(rq, Qb + (size_t)it0 * 64 * 3072, 3072, tid);
  float cpA[2] = {0.f, 0.f}, cpB[2] = {0.f, 0.f};
  for (int it = it0; it < 16; it += 2){
    __syncthreads();
    st64(Qs, rq, tid);
    __syncthreads();
    if (it + 2 < 16) ld64(rq, Qb + (size_t)(it + 2) * 64 * 3072, 3072, tid);
    bool doB = (it >= jtB);
    v4f sa[2][2], sb[2][2];
    #pragma unroll
    for (int a = 0; a < 2; ++a)
      #pragma unroll
      for (int c = 0; c < 2; ++c){ sa[a][c] = vzero(); sb[a][c] = vzero(); }
    #pragma unroll
    for (int kc = 0; kc < 2; ++kc){
      v8bf aq[2], k1[2], k2[2];
      #pragma unroll
      for (int mi = 0; mi < 2; ++mi)
        aq[mi] = *(const v8bf*)(Qs + (wr * 32 + mi * 16 + l15) * 72 + kc * 32 + lg * 8);
      #pragma unroll
      for (int nj = 0; nj < 2; ++nj)
        k1[nj] = *(const v8bf*)(Ka + (wc * 32 + nj * 16 + l15) * 72 + kc * 32 + lg * 8);
      #pragma unroll
      for (int mi = 0; mi < 2; ++mi)
        #pragma unroll
        for (int nj = 0; nj < 2; ++nj)
          sa[mi][nj] = __builtin_amdgcn_mfma_f32_16x16x32_bf16(aq[mi], k1[nj], sa[mi][nj], 0, 0, 0);
      if (doB){
        #pragma unroll
        for (int nj = 0; nj < 2; ++nj)
          k2[nj] = *(const v8bf*)(KbS + (wc * 32 + nj * 16 + l15) * 72 + kc * 32 + lg * 8);
        #pragma unroll
        for (int mi = 0; mi < 2; ++mi)
          #pragma unroll
          for (int nj = 0; nj < 2; ++nj)
            sb[mi][nj] = __builtin_amdgcn_mfma_f32_16x16x32_bf16(aq[mi], k2[nj], sb[mi][nj], 0, 0, 0);
      }
    }
    #pragma unroll
    for (int mi = 0; mi < 2; ++mi)
      #pragma unroll
      for (int nj = 0; nj < 2; ++nj)
        #pragma unroll
        for (int r = 0; r < 4; ++r){
          int il = wr * 32 + mi * 16 + lg * 4 + r;
          int jl = wc * 32 + nj * 16 + l15;
          if (it > jtA || il >= jl) cpA[nj] += __expf(sa[mi][nj][r] * 0.03125f);
          if (doB && (it > jtB || il >= jl)) cpB[nj] += __expf(sb[mi][nj][r] * 0.03125f);
        }
  }
  #pragma unroll
  for (int nj = 0; nj < 2; ++nj){
    float v = cpA[nj];
    v += __shfl_xor(v, 16, 64); v += __shfl_xor(v, 32, 64);
    if (lane < 16) atomicAdd(&colacc[wc * 32 + nj * 16 + l15], v);
    float w = cpB[nj];
    w += __shfl_xor(w, 16, 64); w += __shfl_xor(w, 32, 64);
    if (lane < 16) atomicAdd(&colacc[64 + wc * 32 + nj * 16 + l15], w);
  }
  __syncthreads();
  if (tid < 64)       atomicAdd(&csum[(size_t)bh * 1024 + jtA * 64 + tid], colacc[tid]);
  else if (tid < 128) atomicAdd(&csum[(size_t)bh * 1024 + jtB * 64 + (tid - 64)], colacc[tid]);
}

// ---------------- V' = V * mask/colsum, transposed to [bh][64 d][1024 j] ----------------
__global__ __launch_bounds__(256)
void k_vprep(const uint16_t* __restrict__ QKVg, const float* __restrict__ csum,
             const float* __restrict__ mask, uint16_t* __restrict__ Vp){
  __shared__ __align__(16) uint16_t Vs[128 * 72];
  __shared__ float scb[128];
  int tid = threadIdx.x;
  int bid = blockIdx.x, xcd = bid & 7, idx = bid >> 3;
  int bh = xcd * 8 + (idx & 7);
  int jt = idx >> 3;
  int b = bh >> 4, h = bh & 15;
  int j0 = jt * 128;
  stage64(Vs,           QKVg + ((size_t)(b * 1024 + j0)) * 3072 + 2048 + h * 64, 3072, tid);
  stage64(Vs + 64 * 72, QKVg + ((size_t)(b * 1024 + j0 + 64)) * 3072 + 2048 + h * 64, 3072, tid);
  if (tid < 128) scb[tid] = mask[b * 1024 + j0 + tid] / csum[(size_t)bh * 1024 + j0 + tid];
  __syncthreads();
  int d = tid >> 2, jc = (tid & 3) * 32;
  #pragma unroll
  for (int g8 = 0; g8 < 4; ++g8){
    union { uint16_t h[8]; uint4 v; } o;
    #pragma unroll
    for (int e = 0; e < 8; ++e){
      int j = jc + g8 * 8 + e;
      o.h[e] = f2bf(bf2f(Vs[j * 72 + d]) * scb[j]);
    }
    *(uint4*)(Vp + (size_t)bh * 65536 + (size_t)d * 1024 + j0 + jc + g8 * 8) = o.v;
  }
}

// ---------------- pass 2: O = exp(S) @ V' (swizzled stride-64 LDS, 3 blocks/CU) ----------------
__global__ __launch_bounds__(256, 3)
void k_attnout(const uint16_t* __restrict__ QKVg, const uint16_t* __restrict__ Vp,
               float* __restrict__ out){
  __shared__ __align__(16) uint16_t Qs[128 * 64], Ks[64 * 64], Vt[64 * 64], Ps[128 * 64];
  int tid = threadIdx.x, lane = tid & 63, l15 = lane & 15, lg = lane >> 4, wid = tid >> 6;
  int wr = wid >> 1, wc = wid & 1;
  int sw = l15 & 7;                       // fragment-row swizzle key
  int bid = blockIdx.x, xcd = bid & 7, idx = bid >> 3;
  int bh = xcd * 8 + (idx & 7);
  int p4 = idx >> 3; int pr = (p4 < 4) ? p4 : 11 - p4;
  int b = bh >> 4, h = bh & 15;
  int itA = pr, itB = 15 - pr;
  const uint16_t* Qb = QKVg + (size_t)b * 1024 * 3072 + h * 64;
  const uint16_t* Kb = QKVg + (size_t)b * 1024 * 3072 + 1024 + h * 64;
  const uint16_t* Vb = Vp + (size_t)bh * 65536;
  stage64s(Qs,           Qb + (size_t)itA * 64 * 3072, 3072, tid);
  stage64s(Qs + 64 * 64, Qb + (size_t)itB * 64 * 3072, 3072, tid);
  uint4 rk[2], rv[2];
  ld64(rk, Kb, 3072, tid);
  ld64(rv, Vb, 1024, tid);
  v4f oacc[2][2][2];
  #pragma unroll
  for (int a = 0; a < 2; ++a)
    #pragma unroll
    for (int c = 0; c < 2; ++c)
      #pragma unroll
      for (int d = 0; d < 2; ++d) oacc[a][c][d] = vzero();

  for (int jt = 0; jt <= itB; ++jt){
    __syncthreads();
    st64s(Ks, rk, tid);
    st64s(Vt, rv, tid);
    __syncthreads();
    if (jt < itB){
      ld64(rk, Kb + (size_t)(jt + 1) * 64 * 3072, 3072, tid);
      ld64(rv, Vb + (jt + 1) * 64, 1024, tid);
    }
    #pragma unroll
    for (int half = 0; half < 2; ++half){
      int ith = half ? itB : itA;
      if (jt <= ith){
        v4f sacc[2][2];
        #pragma unroll
        for (int a = 0; a < 2; ++a)
          #pragma unroll
          for (int c = 0; c < 2; ++c) sacc[a][c] = vzero();
        #pragma unroll
        for (int kc = 0; kc < 2; ++kc){
          v8bf ak[2], aq[2];
          int cs = ((kc * 4 + lg) ^ sw) * 8;
          #pragma unroll
          for (int mj = 0; mj < 2; ++mj)
            ak[mj] = *(const v8bf*)(Ks + (wr * 32 + mj * 16 + l15) * 64 + cs);
          #pragma unroll
          for (int ni = 0; ni < 2; ++ni)
            aq[ni] = *(const v8bf*)(Qs + (half * 64 + wc * 32 + ni * 16 + l15) * 64 + cs);
          __builtin_amdgcn_s_setprio(1);
          #pragma unroll
          for (int mj = 0; mj < 2; ++mj)
            #pragma unroll
            for (int ni = 0; ni < 2; ++ni)
              sacc[mj][ni] = __builtin_amdgcn_mfma_f32_16x16x32_bf16(ak[mj], aq[ni], sacc[mj][ni], 0, 0, 0);
          __builtin_amdgcn_s_setprio(0);
        }
        bool diag = (jt == ith);
        #pragma unroll
        for (int mj = 0; mj < 2; ++mj)
          #pragma unroll
          for (int ni = 0; ni < 2; ++ni){
            int iL = wc * 32 + ni * 16 + l15;
            int jb = wr * 32 + mj * 16 + lg * 4;
            float e0 = (!diag || jb + 0 <= iL) ? __expf(sacc[mj][ni][0] * 0.03125f) : 0.f;
            float e1 = (!diag || jb + 1 <= iL) ? __expf(sacc[mj][ni][1] * 0.03125f) : 0.f;
            float e2 = (!diag || jb + 2 <= iL) ? __expf(sacc[mj][ni][2] * 0.03125f) : 0.f;
            float e3 = (!diag || jb + 3 <= iL) ? __expf(sacc[mj][ni][3] * 0.03125f) : 0.f;
            uint2 pk;
            pk.x = (uint32_t)f2bf(e0) | ((uint32_t)f2bf(e1) << 16);
            pk.y = (uint32_t)f2bf(e2) | ((uint32_t)f2bf(e3) << 16);
            // logical (row = half*64+iL, col jb); chunk = jb>>3, swizzled by row&7
            int row = half * 64 + iL;
            int off = row * 64 + (((jb >> 3) ^ (iL & 7)) * 8) + (jb & 7);
            *(uint2*)(Ps + off) = pk;
          }
      }
    }
    __syncthreads();
    #pragma unroll
    for (int half = 0; half < 2; ++half){
      int ith = half ? itB : itA;
      if (jt <= ith){
        #pragma unroll
        for (int kc = 0; kc < 2; ++kc){
          v8bf pa[2], vb_[2];
          int cs = ((kc * 4 + lg) ^ sw) * 8;
          #pragma unroll
          for (int mi = 0; mi < 2; ++mi)
            pa[mi] = *(const v8bf*)(Ps + (half * 64 + wr * 32 + mi * 16 + l15) * 64 + cs);
          #pragma unroll
          for (int nj = 0; nj < 2; ++nj)
            vb_[nj] = *(const v8bf*)(Vt + (wc * 32 + nj * 16 + l15) * 64 + cs);
          __builtin_amdgcn_s_setprio(1);
          #pragma unroll
          for (int mi = 0; mi < 2; ++mi)
            #pragma unroll
            for (int nj = 0; nj < 2; ++nj)
              oacc[half][mi][nj] = __builtin_amdgcn_mfma_f32_16x16x32_bf16(pa[mi], vb_[nj], oacc[half][mi][nj], 0, 0, 0);
          __builtin_amdgcn_s_setprio(0);
        }
      }
    }
  }
  #pragma unroll
  for (int half = 0; half < 2; ++half){
    int ith = half ? itB : itA;
    #pragma unroll
    for (int mi = 0; mi < 2; ++mi)
      #pragma unroll
      for (int nj = 0; nj < 2; ++nj)
        #pragma unroll
        for (int r = 0; r < 4; ++r){
          int ig = ith * 64 + wr * 32 + mi * 16 + lg * 4 + r;
          int d  = wc * 32 + nj * 16 + l15;
          out[((size_t)(b * 1024) + ig) * 1024 + h * 64 + d] = oacc[half][mi][nj][r];
        }
  }
}

extern "C" void kernel_launch(void* const* d_in, const int* in_sizes, int n_in,
                              void* d_out, int out_size, void* d_ws, size_t ws_size,
                              hipStream_t stream) {
  (void)in_sizes; (void)n_in; (void)out_size; (void)ws_size;
  const float* X    = (const float*)d_in[0];
  const float* mask = (const float*)d_in[1];
  const float* Wq   = (const float*)d_in[2];
  const float* bq   = (const float*)d_in[3];
  const float* Wk   = (const float*)d_in[4];
  const float* bk   = (const float*)d_in[5];
  const float* Wv   = (const float*)d_in[6];
  const float* bv   = (const float*)d_in[7];
  const float* Aq   = (const float*)d_in[8];
  const float* Bq   = (const float*)d_in[9];
  const float* Ak   = (const float*)d_in[10];
  const float* Bk   = (const float*)d_in[11];
  const float* Av   = (const float*)d_in[12];
  const float* Bv   = (const float*)d_in[13];
  float* out = (float*)d_out;

  uint16_t* Xb   = (uint16_t*)d_ws;                        // 8 MB
  uint16_t* Weff = Xb + (size_t)4096 * 1024;               // 6 MB  [3072][1024]
  uint16_t* QKV  = Weff + (size_t)3 * 1024 * 1024;         // 24 MB [4096][3072]
  uint16_t* Vp   = QKV + (size_t)4096 * 3072;              // 8 MB  [64][64][1024]
  float*    csum = (float*)(Vp + (size_t)64 * 64 * 1024);  // 256 KB

  k_xcast<<<2048, 256, 0, stream>>>(X, Xb);
  k_zero<<<64, 256, 0, stream>>>(csum);
  k_weff<<<dim3(4096, 3), 256, 0, stream>>>(Wq, Aq, Bq, Wk, Ak, Bk, Wv, Av, Bv, Weff);
  k_gemm<<<768, 256, 0, stream>>>(Xb, Weff, bq, bk, bv, QKV);
  k_colsum<<<1024, 256, 0, stream>>>(QKV, csum);
  k_vprep<<<512, 256, 0, stream>>>(QKV, csum, mask, Vp);
  k_attnout<<<512, 256, 0, stream>>>(QKV, Vp, out);
}